// Round 19
// baseline (616.629 us; speedup 1.0000x reference)
//
#include <hip/hip_runtime.h>
#include <hip/hip_bf16.h>

#define NN 131072   // total nodes (1024 graphs x 128)
#define NG 1024     // graphs
#define NE 1048576  // edges per edge set
#define EB 16384    // edges per binning block
#define NB 64       // binning blocks per set (NE/EB)
#define EMAX 1536   // per-graph edge cap (gat_mfma staging only)

typedef __hip_bfloat16 bf16;
typedef __attribute__((ext_vector_type(8))) short short8v;
typedef __attribute__((ext_vector_type(4))) float f32x4;

__device__ __forceinline__ float b2f(bf16 v){ return __bfloat162float(v); }
__device__ __forceinline__ bf16 f2b(float v){ return __float2bfloat16(v); }
__device__ __forceinline__ unsigned short f2bu(float v){ bf16 b = f2b(v); return *(unsigned short*)&b; }
__device__ __forceinline__ float eluf(float x){ return x > 0.f ? x : expm1f(x); }
__device__ __forceinline__ float lrelu(float x){ return x >= 0.f ? x : 0.2f*x; }

__device__ __forceinline__ float ldx(const void* p, size_t i, int f){
  return f ? ((const float*)p)[i] : b2f(((const bf16*)p)[i]);
}

struct EPtrs { const int *s0,*d0,*s1,*d1,*s2,*d2,*s3,*d3; };

// ---------------- input dtype probe (validated round 4) ----------------
__global__ void detect_dtype(const unsigned short* __restrict__ x, int* __restrict__ flag){
  if (blockIdx.x==0 && threadIdx.x==0){
    int bad = 0;
    for (int i=0;i<2048;i++){
      unsigned short e = (x[i] >> 7) & 0xFF;
      if (e == 0xFF) bad++;
      else if (e >= 0x90) bad++;
      else if (e != 0 && e < 0x60) bad++;
    }
    *flag = (bad > 64) ? 1 : 0;
  }
}

// ---------------- CSR build (validated round 7): block-aggregated graph binning ----------------
__global__ __launch_bounds__(256) void hist_bagg(EPtrs ep, int* __restrict__ Hb){
  __shared__ int cnt[NG];
  int set = blockIdx.y, blk = blockIdx.x, t = threadIdx.x;
  const int* dp = set==0 ? ep.d0 : set==1 ? ep.d1 : set==2 ? ep.d2 : ep.d3;
  for (int i=t;i<NG;i+=256) cnt[i]=0;
  __syncthreads();
  int e0 = blk*EB;
  for (int i=t;i<EB;i+=256) atomicAdd(&cnt[dp[e0+i]>>7],1);
  __syncthreads();
  for (int i=t;i<NG;i+=256) Hb[((size_t)set*NB+blk)*NG+i] = cnt[i];
}

__global__ __launch_bounds__(1024) void scan_bagg(const int* __restrict__ Hb, int* __restrict__ Bb,
                                                  int* __restrict__ base_gs){
  __shared__ int sh[1024];
  int set = blockIdx.x, t = threadIdx.x;
  int run = 0;
  for (int b=0;b<NB;b++){
    int v = Hb[((size_t)set*NB + b)*NG + t];
    Bb[((size_t)set*NB + b)*NG + t] = run;
    run += v;
  }
  int val = run; sh[t] = run; __syncthreads();
  for (int d=1; d<1024; d<<=1){
    int add = (t>=d)? sh[t-d] : 0; __syncthreads();
    val += add; sh[t] = val; __syncthreads();
  }
  int binbase = val - run;
  base_gs[set*(NG+1) + t] = binbase;
  if (t==1023) base_gs[set*(NG+1)+NG] = val;   // == NE
  for (int b=0;b<NB;b++) Bb[((size_t)set*NB + b)*NG + t] += binbase;
}

__global__ __launch_bounds__(256) void scatter_bagg(EPtrs ep, const int* __restrict__ Bb,
                                                    unsigned short* __restrict__ pk){
  __shared__ int cur[NG];
  int set = blockIdx.y, blk = blockIdx.x, t = threadIdx.x;
  const int* sp = set==0 ? ep.s0 : set==1 ? ep.s1 : set==2 ? ep.s2 : ep.s3;
  const int* dp = set==0 ? ep.d0 : set==1 ? ep.d1 : set==2 ? ep.d2 : ep.d3;
  for (int i=t;i<NG;i+=256) cur[i] = Bb[((size_t)set*NB+blk)*NG+i];
  __syncthreads();
  int e0 = blk*EB;
  for (int i=t;i<EB;i+=256){
    int e = e0+i;
    int d = dp[e], s = sp[e];
    int p = atomicAdd(&cur[d>>7],1);
    pk[(size_t)set*NE + p] = (unsigned short)(((d & 127) << 8) | (s & 127));
  }
}

__global__ __launch_bounds__(256) void build_csr(const unsigned short* __restrict__ pk, const int* __restrict__ base,
                                                 unsigned char* __restrict__ srcs8, int* __restrict__ offs4){
  __shared__ int hist[128], excl[128], cur[128];
  __shared__ unsigned char ob[8192];
  int set = blockIdx.y, g = blockIdx.x, t = threadIdx.x;
  int n0 = base[set*(NG+1) + g], n1 = base[set*(NG+1) + g + 1];
  int cnt = min(n1 - n0, 8192);
  if (t < 128) hist[t] = 0;
  __syncthreads();
  const unsigned short* PK = pk + (size_t)set*NE + n0;
  for (int i=t; i<cnt; i+=256) atomicAdd(&hist[PK[i]>>8], 1);
  __syncthreads();
  if (t < 128) excl[t] = hist[t];
  __syncthreads();
  for (int d=1; d<128; d<<=1){
    int v = (t < 128 && t >= d) ? excl[t-d] : 0;
    __syncthreads();
    if (t < 128) excl[t] += v;
    __syncthreads();
  }
  if (t < 128){
    int e_ = excl[t] - hist[t];
    cur[t] = e_;
    offs4[(size_t)set*(NN+1) + g*128 + t] = n0 + e_;
  }
  if (g == NG-1 && t == 0) offs4[(size_t)set*(NN+1) + NN] = NE;
  __syncthreads();
  for (int i=t; i<cnt; i+=256){
    unsigned short v = PK[i];
    int p = atomicAdd(&cur[v>>8], 1);
    ob[p] = (unsigned char)(v & 127);
  }
  __syncthreads();
  unsigned char* S = srcs8 + (size_t)set*NE + n0;
  for (int i=t; i<cnt; i+=256) S[i] = ob[i];
}

// ---------------- weight prep (validated rounds 4/8) ----------------
// sm: 0 att_is[64] | 64 att_id[64] | 128 att_xs[64] | 192 att_ps[128] | 320 att_pd[128] |
//     448 b_intra[64] | 512 b_inter[64] | 576 b_pool[128] | 704 ln_w[128] | 832 ln_b[128]
__global__ __launch_bounds__(256) void prep_kernel(
    const void* w_intra, const void* w_isrc, const void* w_idst, const void* att_xd, const void* w_pool,
    const void* att_is, const void* att_id, const void* att_xs,
    const void* att_ps, const void* att_pd,
    const void* b_intra, const void* b_inter, const void* b_pool,
    const void* ln_w, const void* ln_b,
    bf16* __restrict__ Wtc, bf16* __restrict__ Wtp, float* __restrict__ vdst, float* __restrict__ sm,
    const int* __restrict__ fp){
  int f = *fp;
  int t = threadIdx.x;
  for (int i=t; i<16384; i+=256){
    int j = i & 7, l = (i>>3) & 63, ks = (i>>9) & 3, nt = i >> 11;
    int k = ks*32 + ((l>>4)<<3) + j;
    int c = nt*16 + (l & 15);
    float w1 = (c < 64) ? ldx(w_intra, k*64 + c, f) : ldx(w_isrc, k*64 + (c-64), f);
    Wtc[i] = f2b(w1);
    Wtp[i] = f2b(ldx(w_pool, k*128 + c, f));
  }
  {
    int k = t>>1, h = t&1; float a = 0.f;
    for (int c=0;c<32;c++) a += ldx(w_idst, k*64 + h*32 + c, f) * ldx(att_xd, h*32 + c, f);
    vdst[t] = a;
  }
  if (t < 64){
    sm[t]     = ldx(att_is, t, f);
    sm[64+t]  = ldx(att_id, t, f);
    sm[128+t] = ldx(att_xs, t, f);
    sm[448+t] = ldx(b_intra, t, f);
    sm[512+t] = ldx(b_inter, t, f);
  }
  if (t < 128){
    sm[192+t] = ldx(att_ps, t, f);
    sm[320+t] = ldx(att_pd, t, f);
    sm[576+t] = ldx(b_pool, t, f);
    sm[704+t] = ldx(ln_w, t, f);
    sm[832+t] = ldx(ln_b, t, f);
  }
}

// ---------------- inter-dst logits from raw input (validated round 10) ----------------
__global__ __launch_bounds__(256) void avec_dx_m(const void* Xh, const void* Xt, const float* __restrict__ vdst,
                                                 float* __restrict__ aDx_h, float* __restrict__ aDx_t,
                                                 const int* __restrict__ fp){
  int f = *fp;
  int gid = blockIdx.x*256 + threadIdx.x;
  int n = gid >> 6, lane = gid & 63;
  int side = n >= NN;
  const void* X = side ? Xt : Xh;
  float* aDx = side ? aDx_t : aDx_h;
  int nl = side ? n - NN : n;
  float x1 = eluf(ldx(X, (size_t)nl*128 + lane, f));
  float x2 = eluf(ldx(X, (size_t)nl*128 + 64 + lane, f));
  float t0 = x1*vdst[lane*2+0] + x2*vdst[(lane+64)*2+0];
  float t1 = x1*vdst[lane*2+1] + x2*vdst[(lane+64)*2+1];
  #pragma unroll
  for (int o=32;o;o>>=1){ t0 += __shfl_xor(t0,o); t1 += __shfl_xor(t1,o); }
  if (lane == 0){ aDx[nl*2+0] = t0; aDx[nl*2+1] = t1; }
}

// ---------------- layer-1 v2 (validated r18): full GEMM + both GATs per (graph, side) ----------------
// rep scratch lives in d_out (r16 layout): rep_h at elem 0, rep_t at flag-dependent offset.
__global__ __launch_bounds__(512) void gat_l1v2(
    const void* Xh, const void* Xt,
    const int* __restrict__ offs_h, const unsigned char* __restrict__ srcs_h,
    const int* __restrict__ offs_t, const unsigned char* __restrict__ srcs_t,
    const int* __restrict__ offs_ht, const unsigned char* __restrict__ srcs_ht,
    const int* __restrict__ offs_th, const unsigned char* __restrict__ srcs_th,
    const float* __restrict__ aDx_h, const float* __restrict__ aDx_t,
    bf16* __restrict__ repbase, size_t rept_bf, size_t rept_f32,
    const bf16* __restrict__ Wtc,
    const float* __restrict__ sm, const int* __restrict__ fp){
  __shared__ char U[34816];          // WtL (32 KB) then Pm 128x136 bf16 (34 KB)
  __shared__ bf16 Ft[32*136];
  __shared__ float atab[320];        // att_is|att_id|att_xs|b_intra|b_inter
  __shared__ float2 aSi[128], aDi[128], aSx[128];
  __shared__ float rsum[128];
  __shared__ int begs_i[129], begs_x[129];
  int side = blockIdx.y, g = blockIdx.x, t = threadIdx.x;
  int f = *fp;
  size_t rept = f ? rept_f32 : rept_bf;
  const void* A = side ? Xt : Xh;
  const int* offs_int = side ? offs_t : offs_h;
  const unsigned char* srcs_int = side ? srcs_t : srcs_h;
  const int* offs_ext = side ? offs_th : offs_ht;
  const unsigned char* srcs_ext = side ? srcs_th : srcs_ht;
  const float* aDxo = side ? aDx_h : aDx_t;       // dst side of inter edges
  bf16* rep_self  = repbase + (side ? rept : 0);
  bf16* rep_other = repbase + (side ? 0 : rept);

  bf16* WtL = (bf16*)U;
  {
    const short8v* src = (const short8v*)Wtc;
    short8v* dst = (short8v*)WtL;
    #pragma unroll
    for (int i=0;i<4;i++) dst[t + i*512] = src[t + i*512];
  }
  if (t < 129){ begs_i[t] = offs_int[g*128 + t]; begs_x[t] = offs_ext[g*128 + t]; }
  if (t < 320) atab[t] = sm[ (t<192) ? t : (t<256 ? 448+(t-192) : 512+(t-256)) ];
  __syncthreads();

  int w = t>>6, l = t&63, lr = l&15, lg = l>>4;
  size_t row = (size_t)g*128 + w*16 + lr;
  f32x4 acc[8];
  #pragma unroll
  for (int nt=0;nt<8;nt++) acc[nt] = (f32x4){0.f,0.f,0.f,0.f};
  #pragma unroll
  for (int ks=0;ks<4;ks++){
    short8v af;
    size_t ab = row*128 + ks*32 + lg*8;
    if (f){
      const float* Af = (const float*)A;
      #pragma unroll
      for (int j=0;j<8;j++) ((unsigned short*)&af)[j] = f2bu(eluf(Af[ab+j]));
    } else {
      const unsigned short* Au = (const unsigned short*)A;
      short8v raw = *(const short8v*)(Au + ab);
      #pragma unroll
      for (int j=0;j<8;j++){
        bf16 b; *(unsigned short*)&b = ((unsigned short*)&raw)[j];
        ((unsigned short*)&af)[j] = f2bu(eluf(b2f(b)));
      }
    }
    #pragma unroll
    for (int nt=0;nt<8;nt++){
      short8v bfr = *(const short8v*)((const unsigned short*)WtL + (size_t)((nt*4+ks)*64 + l)*8);
      acc[nt] = __builtin_amdgcn_mfma_f32_16x16x32_bf16(af, bfr, acc[nt], 0, 0, 0);
    }
  }
  // logits from acc (validated epilogue math)
  #pragma unroll
  for (int rg=0; rg<4; ++rg){
    float pS0=0.f,pS1=0.f,pD0=0.f,pD1=0.f,pX0=0.f,pX1=0.f;
    #pragma unroll
    for (int nt=0;nt<8;nt++){
      float v = acc[nt][rg];
      int c = nt*16 + lr;
      if (nt<4){
        float a=atab[c], b=atab[64+c];
        if (nt<2){ pS0+=v*a; pD0+=v*b; } else { pS1+=v*a; pD1+=v*b; }
      } else {
        float xw=atab[128+(c-64)];
        if (nt<6) pX0+=v*xw; else pX1+=v*xw;
      }
    }
    #pragma unroll
    for (int o=1;o<16;o<<=1){
      pS0+=__shfl_xor(pS0,o); pS1+=__shfl_xor(pS1,o);
      pD0+=__shfl_xor(pD0,o); pD1+=__shfl_xor(pD1,o);
      pX0+=__shfl_xor(pX0,o); pX1+=__shfl_xor(pX1,o);
    }
    if (lr == 0){
      int rr = w*16 + lg*4 + rg;
      aSi[rr] = make_float2(pS0, pS1);
      aDi[rr] = make_float2(pD0, pD1);
      aSx[rr] = make_float2(pX0, pX1);
    }
  }
  __syncthreads();   // logits ready; WtL dead

  bf16* Pm = (bf16*)U;
  for (int sx=0; sx<2; ++sx){
    const int* begs = sx ? begs_x : begs_i;
    const unsigned char* srcs = sx ? srcs_ext : srcs_int;
    int gbeg = begs[0];
    bf16* repout = sx ? rep_other : rep_self;
    int col_base = sx ? 64 : 0;
    #pragma unroll
    for (int h=0; h<2; ++h){
      for (int i=t; i<128*68; i+=512) ((unsigned int*)Pm)[i] = 0;
      #pragma unroll
      for (int ntl=0; ntl<2; ++ntl){
        int nt = sx*4 + h*2 + ntl;
        #pragma unroll
        for (int rg=0; rg<4; ++rg)
          ((unsigned short*)Ft)[(ntl*16+lr)*136 + (w*16+lg*4+rg)] = f2bu(acc[nt][rg]);
      }
      __syncthreads();
      if (t < 128){
        int r = t;
        float ad;
        if (sx){ float2 d = ((const float2*)aDxo)[g*128+r]; ad = h ? d.y : d.x; }
        else   { ad = h ? aDi[r].y : aDi[r].x; }
        int b = begs[r]-gbeg, e = begs[r+1]-gbeg;
        float rs = 0.f;
        unsigned short* Pr = (unsigned short*)Pm + r*136;
        const float2* aSt = sx ? aSx : aSi;
        for (int j=b; j<e; ++j){
          int s = srcs[gbeg + j];
          float as = h ? aSt[s].y : aSt[s].x;
          float p = __expf(lrelu(as + ad));
          bf16 ov; *(unsigned short*)&ov = Pr[s];
          Pr[s] = f2bu(b2f(ov) + p);
          rs += p;
        }
        if (sx == 0){
          float as = h ? aSt[r].y : aSt[r].x;
          float p = __expf(lrelu(as + ad));
          bf16 ov; *(unsigned short*)&ov = Pr[r];
          Pr[r] = f2bu(b2f(ov) + p);
          rs += p;
        }
        rsum[r] = rs;
      }
      __syncthreads();
      f32x4 a2[2];
      a2[0] = (f32x4){0.f,0.f,0.f,0.f}; a2[1] = (f32x4){0.f,0.f,0.f,0.f};
      #pragma unroll
      for (int ks=0;ks<4;ks++){
        short8v af = *(const short8v*)((const unsigned short*)Pm + (w*16+lr)*136 + ks*32 + lg*8);
        #pragma unroll
        for (int j=0;j<2;j++){
          short8v bfr = *(const short8v*)((const unsigned short*)Ft + (j*16+lr)*136 + ks*32 + lg*8);
          a2[j] = __builtin_amdgcn_mfma_f32_16x16x32_bf16(af, bfr, a2[j], 0, 0, 0);
        }
      }
      #pragma unroll
      for (int rg=0; rg<4; ++rg){
        int rrow = w*16 + lg*4 + rg;
        float rinv = 1.f / (rsum[rrow] + 1e-16f);
        size_t n = (size_t)g*128 + rrow;
        #pragma unroll
        for (int j=0;j<2;j++){
          int c = h*32 + j*16 + lr;
          float o = a2[j][rg]*rinv + atab[(sx?256:192) + c];
          repout[n*128 + col_base + c] = f2b(o);
        }
      }
      __syncthreads();
    }
  }
}

// ---------------- graph LayerNorm + ELU, single-pass, d_out-resident (validated r16) ----------------
__global__ __launch_bounds__(512) void graph_ln_m(bf16* R_, size_t off_t_bf, size_t off_t_f32,
    const int* __restrict__ fsel, const float* __restrict__ wv, const float* __restrict__ bv){
  __shared__ float sh1[8], sh2[8];
  int g = blockIdx.x, t = threadIdx.x;
  int side = g >> 10, gl = g & 1023;
  size_t soff = side ? ((*fsel) ? off_t_f32 : off_t_bf) : 0;
  unsigned short* Ru = (unsigned short*)(R_ + soff + (size_t)gl*16384);
  short8v v[4];
  #pragma unroll
  for (int q=0;q<4;q++) v[q] = *(short8v*)(Ru + q*4096 + t*8);
  float s1=0.f, s2=0.f;
  #pragma unroll
  for (int q=0;q<4;q++)
    #pragma unroll
    for (int j=0;j<8;j++){
      bf16 b; *(unsigned short*)&b = ((unsigned short*)&v[q])[j];
      float x = b2f(b); s1 += x; s2 += x*x;
    }
  #pragma unroll
  for (int o=32;o;o>>=1){ s1 += __shfl_xor(s1,o); s2 += __shfl_xor(s2,o); }
  if ((t&63)==0){ sh1[t>>6]=s1; sh2[t>>6]=s2; }
  __syncthreads();
  float S1=0.f,S2=0.f;
  #pragma unroll
  for (int i=0;i<8;i++){ S1+=sh1[i]; S2+=sh2[i]; }
  float mean = S1 * (1.f/16384.f);
  float var = fmaxf(S2*(1.f/16384.f) - mean*mean, 0.f);
  float rstd = rsqrtf(var + 1e-5f);
  #pragma unroll
  for (int q=0;q<4;q++){
    short8v ov;
    #pragma unroll
    for (int j=0;j<8;j++){
      int c = (t*8 + j) & 127;
      bf16 b; *(unsigned short*)&b = ((unsigned short*)&v[q])[j];
      float y = (b2f(b)-mean)*rstd*wv[c] + bv[c];
      ((unsigned short*)&ov)[j] = f2bu(y>0.f ? y : expm1f(y));
    }
    *(short8v*)(Ru + q*4096 + t*8) = ov;
  }
}

// ---------------- pool GEMM (validated r16): d_out rep -> AB (ws), fused aSp/aDp ----------------
__global__ __launch_bounds__(512) void gemm_pool(const bf16* __restrict__ repbase, size_t rept_bf, size_t rept_f32,
    const bf16* __restrict__ Wtp, const float* __restrict__ sm,
    bf16* __restrict__ AB_h, bf16* __restrict__ AB_t,
    float* __restrict__ aSp_h, float* __restrict__ aDp_h,
    float* __restrict__ aSp_t, float* __restrict__ aDp_t,
    const int* __restrict__ fsel){
  __shared__ bf16 WtL[16384];
  __shared__ float attL[256];
  int side = blockIdx.x >> 10;
  int bx = blockIdx.x & 1023;
  size_t rept = (*fsel) ? rept_f32 : rept_bf;
  const unsigned short* A = (const unsigned short*)(repbase + (side ? rept : 0));
  bf16* C = side ? AB_t : AB_h;
  float* oS = side ? aSp_t : aSp_h;
  float* oD = side ? aDp_t : aDp_h;
  int tid = threadIdx.x;
  {
    const short8v* src = (const short8v*)Wtp;
    short8v* dst = (short8v*)WtL;
    #pragma unroll
    for (int i=0;i<4;i++) dst[tid + i*512] = src[tid + i*512];
    if (tid < 256) attL[tid] = sm[(tid<128) ? 192+tid : 320+(tid-128)];
  }
  __syncthreads();
  int w = tid >> 6, l = tid & 63;
  int lr = l & 15, lg = l >> 4;
  size_t row = (size_t)bx*128 + w*16 + lr;
  f32x4 acc[8];
  #pragma unroll
  for (int nt=0;nt<8;nt++) acc[nt] = (f32x4){0.f,0.f,0.f,0.f};
  #pragma unroll
  for (int ks=0;ks<4;ks++){
    short8v af = *(const short8v*)(A + row*128 + ks*32 + lg*8);
    #pragma unroll
    for (int nt=0;nt<8;nt++){
      short8v bfr = *(const short8v*)((const unsigned short*)WtL + (size_t)((nt*4+ks)*64 + l)*8);
      acc[nt] = __builtin_amdgcn_mfma_f32_16x16x32_bf16(af, bfr, acc[nt], 0, 0, 0);
    }
  }
  size_t crow = (size_t)bx*128 + w*16 + lg*4;
  #pragma unroll
  for (int nt=0;nt<8;nt++)
    #pragma unroll
    for (int r=0;r<4;r++)
      C[(crow + r)*128 + nt*16 + lr] = f2b(acc[nt][r]);
  #pragma unroll
  for (int rg=0; rg<4; ++rg){
    float pS0=0.f,pS1=0.f,pD0=0.f,pD1=0.f;
    #pragma unroll
    for (int nt=0;nt<8;nt++){
      float v = acc[nt][rg];
      int c = nt*16 + lr;
      float a=attL[c], b=attL[128+c];
      if (nt<4){ pS0+=v*a; pD0+=v*b; } else { pS1+=v*a; pD1+=v*b; }
    }
    #pragma unroll
    for (int o=1;o<16;o<<=1){
      pS0+=__shfl_xor(pS0,o); pS1+=__shfl_xor(pS1,o);
      pD0+=__shfl_xor(pD0,o); pD1+=__shfl_xor(pD1,o);
    }
    if (lr == 0){
      size_t n = crow + rg;
      oS[n*2]=pS0; oS[n*2+1]=pS1;
      oD[n*2]=pD0; oD[n*2+1]=pD1;
    }
  }
}

// ---------------- GAT aggregation v6 (validated rounds 12/16) ----------------
struct GatSet {
  const int* offs;
  const unsigned char* srcs;
  const bf16* F;
  const float* aS;
  const float* aD;
  const float* bias;
  int col_in;
  int self_loops;
  int col_off;
  int pad;
  size_t obase_bf, obase_f32, gbase;
};
struct GatSet4 { GatSet s[4]; };

template<int FD>
__global__ __launch_bounds__(512) void gat_mfma(GatSet4 sets, void* out,
    const int* __restrict__ fp, const int* __restrict__ fsel){
  constexpr int NH = FD/2;
  constexpr int NT = NH/16;
  constexpr int KSH = (FD==64)?5:6;
  __shared__ bf16 Ft[NH*136];
  __shared__ bf16 Pm[128*136];
  __shared__ float2 aSs[128];
  __shared__ float rsum[128];
  __shared__ unsigned char ss[EMAX];
  __shared__ int begs[129];
  const GatSet S = sets.s[blockIdx.y];
  int fo = fp ? *fp : -1;
  size_t obase = (fsel && *fsel) ? S.obase_f32 : S.obase_bf;
  int g = blockIdx.x, t = threadIdx.x;

  if (t < 129) begs[t] = S.offs[g*128 + t];
  if (t >= 256 && t < 384) aSs[t-256] = ((const float2*)S.aS)[g*128 + (t-256)];
  __syncthreads();
  int gbeg = begs[0];
  int Eg = min(begs[128] - gbeg, EMAX);
  int w = t >> 6, l = t & 63, lr = l & 15, lg = l >> 4;

  #pragma unroll
  for (int h=0; h<2; ++h){
    for (int i=t; i<128*68; i+=512) ((unsigned int*)Pm)[i] = 0;
    if (h==0) for (int i=t; i<Eg; i+=512) ss[i] = S.srcs[gbeg + i];
    __syncthreads();
    if (t < 128){
      int r = t;
      float ad = S.aD[(size_t)(g*128+r)*2 + h];
      int b = begs[r]-gbeg, e = min(begs[r+1]-gbeg, EMAX);
      float rs = 0.f;
      unsigned short* Pr = (unsigned short*)Pm + r*136;
      for (int j=b; j<e; ++j){
        int s = ss[j];
        float2 as2 = aSs[s];
        float p = __expf(lrelu((h ? as2.y : as2.x) + ad));
        bf16 ov; *(unsigned short*)&ov = Pr[s];
        Pr[s] = f2bu(b2f(ov) + p);
        rs += p;
      }
      if (S.self_loops){
        float2 as2 = aSs[r];
        float p = __expf(lrelu((h ? as2.y : as2.x) + ad));
        bf16 ov; *(unsigned short*)&ov = Pr[r];
        Pr[r] = f2bu(b2f(ov) + p);
        rs += p;
      }
      rsum[r] = rs;
    } else {
      const unsigned short* Fu = (const unsigned short*)S.F;
      unsigned short* FtU = (unsigned short*)Ft;
      int ft = t - 128;
      for (int i=ft; i<NH*128; i+=384){
        int c = i & (NH-1), k = i >> KSH;
        FtU[c*136 + k] = Fu[((size_t)(g*128+k))*128 + S.col_in + h*NH + c];
      }
    }
    __syncthreads();
    f32x4 acc[NT];
    #pragma unroll
    for (int nt=0;nt<NT;nt++) acc[nt] = (f32x4){0.f,0.f,0.f,0.f};
    #pragma unroll
    for (int ks=0;ks<4;ks++){
      short8v af = *(const short8v*)((const unsigned short*)Pm + (w*16+lr)*136 + ks*32 + lg*8);
      #pragma unroll
      for (int nt=0;nt<NT;nt++){
        short8v bfr = *(const short8v*)((const unsigned short*)Ft + (nt*16 + lr)*136 + ks*32 + lg*8);
        acc[nt] = __builtin_amdgcn_mfma_f32_16x16x32_bf16(af, bfr, acc[nt], 0, 0, 0);
      }
    }
    #pragma unroll
    for (int rg=0; rg<4; ++rg){
      int rrow = w*16 + lg*4 + rg;
      float rinv = 1.f / (rsum[rrow] + 1e-16f);
      int n = g*128 + rrow;
      bool gw = (fp != nullptr) && (rrow == 127);
      #pragma unroll
      for (int nt=0;nt<NT;nt++){
        int c = h*NH + nt*16 + lr;
        float o = acc[nt][rg]*rinv + S.bias[c];
        size_t oi = obase + (size_t)n*128 + S.col_off + c;
        if (fo > 0){
          ((float*)out)[oi] = o;
          if (gw) ((float*)out)[S.gbase + (size_t)g*128 + c] = o;
        } else {
          ((bf16*)out)[oi] = f2b(o);
          if (gw) ((bf16*)out)[S.gbase + (size_t)g*128 + c] = f2b(o);
        }
      }
    }
    __syncthreads();
  }
}

extern "C" void kernel_launch(void* const* d_in, const int* in_sizes, int n_in,
                              void* d_out, int out_size, void* d_ws, size_t ws_size,
                              hipStream_t stream){
  (void)in_sizes; (void)n_in; (void)out_size; (void)ws_size;
  const void* h_x = d_in[0];
  const void* t_x = d_in[1];
  const int* h_ei = (const int*)d_in[2];
  const int* t_ei = (const int*)d_in[3];
  const int* b_ei = (const int*)d_in[4];

  // ---- workspace (~90 MB; < 96.7 MB proven round 4) ----
  char* base = (char*)d_ws;
  size_t off = 0;
  auto alloc = [&](size_t bytes)->char*{ char* p = base + off; off += (bytes + 255) & ~(size_t)255; return p; };
  bf16* AB_h     = (bf16*)alloc((size_t)NN*128*2);   // pool feats h
  bf16* AB_t     = (bf16*)alloc((size_t)NN*128*2);   // pool feats t
  unsigned short* pk = (unsigned short*)alloc((size_t)4*NE*2);
  unsigned char* srcs8 = (unsigned char*)alloc((size_t)4*NE);
  int* offs4     = (int*)alloc((size_t)4*(NN+1)*4);
  int* Hb        = (int*)alloc((size_t)4*NB*NG*4);
  int* Bb        = (int*)alloc((size_t)4*NB*NG*4);
  int* base_gs   = (int*)alloc((size_t)4*(NG+1)*4);
  float* aDx_h   = (float*)alloc((size_t)NN*2*4);
  float* aDx_t   = (float*)alloc((size_t)NN*2*4);
  float* aSp_h   = (float*)alloc((size_t)NN*2*4);
  float* aDp_h   = (float*)alloc((size_t)NN*2*4);
  float* aSp_t   = (float*)alloc((size_t)NN*2*4);
  float* aDp_t   = (float*)alloc((size_t)NN*2*4);
  bf16* Wtc      = (bf16*)alloc(16384*2);
  bf16* Wtp      = (bf16*)alloc(16384*2);
  float* vdst    = (float*)alloc(256*4);
  float* sm      = (float*)alloc(960*4);
  int* flag      = (int*)alloc(256);

  // rep scratch in d_out (validated r4-r16 layout): rep_h at 0; rep_t flag-dependent
  const size_t REPT_BF = (size_t)NN*128, REPT_F32 = (size_t)2*NN*128;

  detect_dtype<<<1,64,0,stream>>>((const unsigned short*)h_x, flag);

  EPtrs ep;
  ep.s0 = h_ei;      ep.d0 = h_ei + NE;
  ep.s1 = t_ei;      ep.d1 = t_ei + NE;
  ep.s2 = b_ei;      ep.d2 = b_ei + NE;
  ep.s3 = b_ei + NE; ep.d3 = b_ei;
  hist_bagg<<<dim3(NB,4),256,0,stream>>>(ep, Hb);
  scan_bagg<<<4,1024,0,stream>>>(Hb, Bb, base_gs);
  scatter_bagg<<<dim3(NB,4),256,0,stream>>>(ep, Bb, pk);
  build_csr<<<dim3(NG,4),256,0,stream>>>(pk, base_gs, srcs8, offs4);

  prep_kernel<<<1,256,0,stream>>>(d_in[9], d_in[13], d_in[14], d_in[16], d_in[18],
      d_in[10], d_in[11], d_in[15], d_in[19], d_in[20],
      d_in[12], d_in[17], d_in[21], d_in[22], d_in[23],
      Wtc, Wtp, vdst, sm, flag);

  avec_dx_m<<<65536,256,0,stream>>>(h_x, t_x, vdst, aDx_h, aDx_t, flag);

  const int* offs_h = offs4;
  const int* offs_t = offs4 + (NN+1);
  const int* offs_ht= offs4 + 2*(NN+1);
  const int* offs_th= offs4 + 3*(NN+1);
  const unsigned char* srcs_h = srcs8;
  const unsigned char* srcs_t = srcs8 + NE;
  const unsigned char* srcs_ht= srcs8 + (size_t)2*NE;
  const unsigned char* srcs_th= srcs8 + (size_t)3*NE;

  // ---- layer-1: full GEMM + both GATs per (graph, side); rep -> d_out scratch ----
  gat_l1v2<<<dim3(NG,2),512,0,stream>>>(h_x, t_x,
      offs_h, srcs_h, offs_t, srcs_t, offs_ht, srcs_ht, offs_th, srcs_th,
      aDx_h, aDx_t, (bf16*)d_out, REPT_BF, REPT_F32, Wtc, sm, flag);

  // ---- graph LayerNorm + ELU on d_out rep (both sides) ----
  graph_ln_m<<<2048,512,0,stream>>>((bf16*)d_out, REPT_BF, REPT_F32, flag, sm+704, sm+832);

  // ---- pool GEMM: d_out rep -> AB (ws) + fused logits ----
  gemm_pool<<<2048,512,0,stream>>>((const bf16*)d_out, REPT_BF, REPT_F32, Wtp, sm,
      AB_h, AB_t, aSp_h, aDp_h, aSp_t, aDp_t, flag);

  // ---- pool GATs -> d_out + gathers (validated v6) ----
  {
    size_t gb_h = (size_t)2*NN*128;
    size_t gb_t = gb_h + (size_t)NG*128;
    GatSet4 P;
    P.s[0] = { offs_h, srcs_h, AB_h, aSp_h, aDp_h, sm+576, 0, 1, 0, 0, 0,              0,              gb_h };
    P.s[1] = { offs_t, srcs_t, AB_t, aSp_t, aDp_t, sm+576, 0, 1, 0, 0, (size_t)NN*128, (size_t)NN*128, gb_t };
    P.s[2] = P.s[0]; P.s[3] = P.s[0];
    gat_mfma<128><<<dim3(NG,2),512,0,stream>>>(P, d_out, flag, flag);
  }
}

// Round 20
// 611.682 us; speedup vs baseline: 1.0081x; 1.0081x over previous
//
#include <hip/hip_runtime.h>
#include <hip/hip_bf16.h>

#define NN 131072   // total nodes (1024 graphs x 128)
#define NG 1024     // graphs
#define NE 1048576  // edges per edge set
#define EB 16384    // edges per binning block
#define NB 64       // binning blocks per set (NE/EB)
#define EMAX 1536   // per-graph edge cap (gat_mfma staging only)

typedef __hip_bfloat16 bf16;
typedef __attribute__((ext_vector_type(8))) short short8v;
typedef __attribute__((ext_vector_type(4))) float f32x4;

__device__ __forceinline__ float b2f(bf16 v){ return __bfloat162float(v); }
__device__ __forceinline__ bf16 f2b(float v){ return __float2bfloat16(v); }
__device__ __forceinline__ unsigned short f2bu(float v){ bf16 b = f2b(v); return *(unsigned short*)&b; }
__device__ __forceinline__ float eluf(float x){ return x > 0.f ? x : expm1f(x); }
__device__ __forceinline__ float lrelu(float x){ return x >= 0.f ? x : 0.2f*x; }

__device__ __forceinline__ float ldx(const void* p, size_t i, int f){
  return f ? ((const float*)p)[i] : b2f(((const bf16*)p)[i]);
}

struct EPtrs { const int *s0,*d0,*s1,*d1,*s2,*d2,*s3,*d3; };

// ---------------- input dtype probe (validated round 4) ----------------
__global__ void detect_dtype(const unsigned short* __restrict__ x, int* __restrict__ flag){
  if (blockIdx.x==0 && threadIdx.x==0){
    int bad = 0;
    for (int i=0;i<2048;i++){
      unsigned short e = (x[i] >> 7) & 0xFF;
      if (e == 0xFF) bad++;
      else if (e >= 0x90) bad++;
      else if (e != 0 && e < 0x60) bad++;
    }
    *flag = (bad > 64) ? 1 : 0;
  }
}

// ---------------- CSR build (validated round 7): block-aggregated graph binning ----------------
__global__ __launch_bounds__(256) void hist_bagg(EPtrs ep, int* __restrict__ Hb){
  __shared__ int cnt[NG];
  int set = blockIdx.y, blk = blockIdx.x, t = threadIdx.x;
  const int* dp = set==0 ? ep.d0 : set==1 ? ep.d1 : set==2 ? ep.d2 : ep.d3;
  for (int i=t;i<NG;i+=256) cnt[i]=0;
  __syncthreads();
  int e0 = blk*EB;
  for (int i=t;i<EB;i+=256) atomicAdd(&cnt[dp[e0+i]>>7],1);
  __syncthreads();
  for (int i=t;i<NG;i+=256) Hb[((size_t)set*NB+blk)*NG+i] = cnt[i];
}

__global__ __launch_bounds__(1024) void scan_bagg(const int* __restrict__ Hb, int* __restrict__ Bb,
                                                  int* __restrict__ base_gs){
  __shared__ int sh[1024];
  int set = blockIdx.x, t = threadIdx.x;
  int run = 0;
  for (int b=0;b<NB;b++){
    int v = Hb[((size_t)set*NB + b)*NG + t];
    Bb[((size_t)set*NB + b)*NG + t] = run;
    run += v;
  }
  int val = run; sh[t] = run; __syncthreads();
  for (int d=1; d<1024; d<<=1){
    int add = (t>=d)? sh[t-d] : 0; __syncthreads();
    val += add; sh[t] = val; __syncthreads();
  }
  int binbase = val - run;
  base_gs[set*(NG+1) + t] = binbase;
  if (t==1023) base_gs[set*(NG+1)+NG] = val;   // == NE
  for (int b=0;b<NB;b++) Bb[((size_t)set*NB + b)*NG + t] += binbase;
}

__global__ __launch_bounds__(256) void scatter_bagg(EPtrs ep, const int* __restrict__ Bb,
                                                    unsigned short* __restrict__ pk){
  __shared__ int cur[NG];
  int set = blockIdx.y, blk = blockIdx.x, t = threadIdx.x;
  const int* sp = set==0 ? ep.s0 : set==1 ? ep.s1 : set==2 ? ep.s2 : ep.s3;
  const int* dp = set==0 ? ep.d0 : set==1 ? ep.d1 : set==2 ? ep.d2 : ep.d3;
  for (int i=t;i<NG;i+=256) cur[i] = Bb[((size_t)set*NB+blk)*NG+i];
  __syncthreads();
  int e0 = blk*EB;
  for (int i=t;i<EB;i+=256){
    int e = e0+i;
    int d = dp[e], s = sp[e];
    int p = atomicAdd(&cur[d>>7],1);
    pk[(size_t)set*NE + p] = (unsigned short)(((d & 127) << 8) | (s & 127));
  }
}

__global__ __launch_bounds__(256) void build_csr(const unsigned short* __restrict__ pk, const int* __restrict__ base,
                                                 unsigned char* __restrict__ srcs8, int* __restrict__ offs4){
  __shared__ int hist[128], excl[128], cur[128];
  __shared__ unsigned char ob[8192];
  int set = blockIdx.y, g = blockIdx.x, t = threadIdx.x;
  int n0 = base[set*(NG+1) + g], n1 = base[set*(NG+1) + g + 1];
  int cnt = min(n1 - n0, 8192);
  if (t < 128) hist[t] = 0;
  __syncthreads();
  const unsigned short* PK = pk + (size_t)set*NE + n0;
  for (int i=t; i<cnt; i+=256) atomicAdd(&hist[PK[i]>>8], 1);
  __syncthreads();
  if (t < 128) excl[t] = hist[t];
  __syncthreads();
  for (int d=1; d<128; d<<=1){
    int v = (t < 128 && t >= d) ? excl[t-d] : 0;
    __syncthreads();
    if (t < 128) excl[t] += v;
    __syncthreads();
  }
  if (t < 128){
    int e_ = excl[t] - hist[t];
    cur[t] = e_;
    offs4[(size_t)set*(NN+1) + g*128 + t] = n0 + e_;
  }
  if (g == NG-1 && t == 0) offs4[(size_t)set*(NN+1) + NN] = NE;
  __syncthreads();
  for (int i=t; i<cnt; i+=256){
    unsigned short v = PK[i];
    int p = atomicAdd(&cur[v>>8], 1);
    ob[p] = (unsigned char)(v & 127);
  }
  __syncthreads();
  unsigned char* S = srcs8 + (size_t)set*NE + n0;
  for (int i=t; i<cnt; i+=256) S[i] = ob[i];
}

// ---------------- weight prep (validated rounds 4/8) ----------------
// sm: 0 att_is[64] | 64 att_id[64] | 128 att_xs[64] | 192 att_ps[128] | 320 att_pd[128] |
//     448 b_intra[64] | 512 b_inter[64] | 576 b_pool[128] | 704 ln_w[128] | 832 ln_b[128]
__global__ __launch_bounds__(256) void prep_kernel(
    const void* w_intra, const void* w_isrc, const void* w_idst, const void* att_xd, const void* w_pool,
    const void* att_is, const void* att_id, const void* att_xs,
    const void* att_ps, const void* att_pd,
    const void* b_intra, const void* b_inter, const void* b_pool,
    const void* ln_w, const void* ln_b,
    bf16* __restrict__ Wtc, bf16* __restrict__ Wtp, float* __restrict__ vdst, float* __restrict__ sm,
    const int* __restrict__ fp){
  int f = *fp;
  int t = threadIdx.x;
  for (int i=t; i<16384; i+=256){
    int j = i & 7, l = (i>>3) & 63, ks = (i>>9) & 3, nt = i >> 11;
    int k = ks*32 + ((l>>4)<<3) + j;
    int c = nt*16 + (l & 15);
    float w1 = (c < 64) ? ldx(w_intra, k*64 + c, f) : ldx(w_isrc, k*64 + (c-64), f);
    Wtc[i] = f2b(w1);
    Wtp[i] = f2b(ldx(w_pool, k*128 + c, f));
  }
  {
    int k = t>>1, h = t&1; float a = 0.f;
    for (int c=0;c<32;c++) a += ldx(w_idst, k*64 + h*32 + c, f) * ldx(att_xd, h*32 + c, f);
    vdst[t] = a;
  }
  if (t < 64){
    sm[t]     = ldx(att_is, t, f);
    sm[64+t]  = ldx(att_id, t, f);
    sm[128+t] = ldx(att_xs, t, f);
    sm[448+t] = ldx(b_intra, t, f);
    sm[512+t] = ldx(b_inter, t, f);
  }
  if (t < 128){
    sm[192+t] = ldx(att_ps, t, f);
    sm[320+t] = ldx(att_pd, t, f);
    sm[576+t] = ldx(b_pool, t, f);
    sm[704+t] = ldx(ln_w, t, f);
    sm[832+t] = ldx(ln_b, t, f);
  }
}

// ---------------- inter-dst logits from raw input (validated round 10) ----------------
__global__ __launch_bounds__(256) void avec_dx_m(const void* Xh, const void* Xt, const float* __restrict__ vdst,
                                                 float* __restrict__ aDx_h, float* __restrict__ aDx_t,
                                                 const int* __restrict__ fp){
  int f = *fp;
  int gid = blockIdx.x*256 + threadIdx.x;
  int n = gid >> 6, lane = gid & 63;
  int side = n >= NN;
  const void* X = side ? Xt : Xh;
  float* aDx = side ? aDx_t : aDx_h;
  int nl = side ? n - NN : n;
  float x1 = eluf(ldx(X, (size_t)nl*128 + lane, f));
  float x2 = eluf(ldx(X, (size_t)nl*128 + 64 + lane, f));
  float t0 = x1*vdst[lane*2+0] + x2*vdst[(lane+64)*2+0];
  float t1 = x1*vdst[lane*2+1] + x2*vdst[(lane+64)*2+1];
  #pragma unroll
  for (int o=32;o;o>>=1){ t0 += __shfl_xor(t0,o); t1 += __shfl_xor(t1,o); }
  if (lane == 0){ aDx[nl*2+0] = t0; aDx[nl*2+1] = t1; }
}

// ---------------- layer-1 v2 (validated r18): full GEMM + both GATs per (graph, side) ----------------
// rep scratch lives in d_out (r16 layout): rep_h at elem 0, rep_t at flag-dependent offset.
__global__ __launch_bounds__(512) void gat_l1v2(
    const void* Xh, const void* Xt,
    const int* __restrict__ offs_h, const unsigned char* __restrict__ srcs_h,
    const int* __restrict__ offs_t, const unsigned char* __restrict__ srcs_t,
    const int* __restrict__ offs_ht, const unsigned char* __restrict__ srcs_ht,
    const int* __restrict__ offs_th, const unsigned char* __restrict__ srcs_th,
    const float* __restrict__ aDx_h, const float* __restrict__ aDx_t,
    bf16* __restrict__ repbase, size_t rept_bf, size_t rept_f32,
    const bf16* __restrict__ Wtc,
    const float* __restrict__ sm, const int* __restrict__ fp){
  __shared__ char U[34816];          // WtL (32 KB) then Pm 128x136 bf16 (34 KB)
  __shared__ bf16 Ft[32*136];
  __shared__ float atab[320];        // att_is|att_id|att_xs|b_intra|b_inter
  __shared__ float2 aSi[128], aDi[128], aSx[128];
  __shared__ float rsum[128];
  __shared__ int begs_i[129], begs_x[129];
  int side = blockIdx.y, g = blockIdx.x, t = threadIdx.x;
  int f = *fp;
  size_t rept = f ? rept_f32 : rept_bf;
  const void* A = side ? Xt : Xh;
  const int* offs_int = side ? offs_t : offs_h;
  const unsigned char* srcs_int = side ? srcs_t : srcs_h;
  const int* offs_ext = side ? offs_th : offs_ht;
  const unsigned char* srcs_ext = side ? srcs_th : srcs_ht;
  const float* aDxo = side ? aDx_h : aDx_t;       // dst side of inter edges
  bf16* rep_self  = repbase + (side ? rept : 0);
  bf16* rep_other = repbase + (side ? 0 : rept);

  bf16* WtL = (bf16*)U;
  {
    const short8v* src = (const short8v*)Wtc;
    short8v* dst = (short8v*)WtL;
    #pragma unroll
    for (int i=0;i<4;i++) dst[t + i*512] = src[t + i*512];
  }
  if (t < 129){ begs_i[t] = offs_int[g*128 + t]; begs_x[t] = offs_ext[g*128 + t]; }
  if (t < 320) atab[t] = sm[ (t<192) ? t : (t<256 ? 448+(t-192) : 512+(t-256)) ];
  __syncthreads();

  int w = t>>6, l = t&63, lr = l&15, lg = l>>4;
  size_t row = (size_t)g*128 + w*16 + lr;
  f32x4 acc[8];
  #pragma unroll
  for (int nt=0;nt<8;nt++) acc[nt] = (f32x4){0.f,0.f,0.f,0.f};
  #pragma unroll
  for (int ks=0;ks<4;ks++){
    short8v af;
    size_t ab = row*128 + ks*32 + lg*8;
    if (f){
      const float* Af = (const float*)A;
      #pragma unroll
      for (int j=0;j<8;j++) ((unsigned short*)&af)[j] = f2bu(eluf(Af[ab+j]));
    } else {
      const unsigned short* Au = (const unsigned short*)A;
      short8v raw = *(const short8v*)(Au + ab);
      #pragma unroll
      for (int j=0;j<8;j++){
        bf16 b; *(unsigned short*)&b = ((unsigned short*)&raw)[j];
        ((unsigned short*)&af)[j] = f2bu(eluf(b2f(b)));
      }
    }
    #pragma unroll
    for (int nt=0;nt<8;nt++){
      short8v bfr = *(const short8v*)((const unsigned short*)WtL + (size_t)((nt*4+ks)*64 + l)*8);
      acc[nt] = __builtin_amdgcn_mfma_f32_16x16x32_bf16(af, bfr, acc[nt], 0, 0, 0);
    }
  }
  // logits from acc (validated epilogue math)
  #pragma unroll
  for (int rg=0; rg<4; ++rg){
    float pS0=0.f,pS1=0.f,pD0=0.f,pD1=0.f,pX0=0.f,pX1=0.f;
    #pragma unroll
    for (int nt=0;nt<8;nt++){
      float v = acc[nt][rg];
      int c = nt*16 + lr;
      if (nt<4){
        float a=atab[c], b=atab[64+c];
        if (nt<2){ pS0+=v*a; pD0+=v*b; } else { pS1+=v*a; pD1+=v*b; }
      } else {
        float xw=atab[128+(c-64)];
        if (nt<6) pX0+=v*xw; else pX1+=v*xw;
      }
    }
    #pragma unroll
    for (int o=1;o<16;o<<=1){
      pS0+=__shfl_xor(pS0,o); pS1+=__shfl_xor(pS1,o);
      pD0+=__shfl_xor(pD0,o); pD1+=__shfl_xor(pD1,o);
      pX0+=__shfl_xor(pX0,o); pX1+=__shfl_xor(pX1,o);
    }
    if (lr == 0){
      int rr = w*16 + lg*4 + rg;
      aSi[rr] = make_float2(pS0, pS1);
      aDi[rr] = make_float2(pD0, pD1);
      aSx[rr] = make_float2(pX0, pX1);
    }
  }
  __syncthreads();   // logits ready; WtL dead

  bf16* Pm = (bf16*)U;
  for (int sx=0; sx<2; ++sx){
    const int* begs = sx ? begs_x : begs_i;
    const unsigned char* srcs = sx ? srcs_ext : srcs_int;
    int gbeg = begs[0];
    bf16* repout = sx ? rep_other : rep_self;
    int col_base = sx ? 64 : 0;
    #pragma unroll
    for (int h=0; h<2; ++h){
      for (int i=t; i<128*68; i+=512) ((unsigned int*)Pm)[i] = 0;
      #pragma unroll
      for (int ntl=0; ntl<2; ++ntl){
        int nt = sx*4 + h*2 + ntl;
        #pragma unroll
        for (int rg=0; rg<4; ++rg)
          ((unsigned short*)Ft)[(ntl*16+lr)*136 + (w*16+lg*4+rg)] = f2bu(acc[nt][rg]);
      }
      __syncthreads();
      if (t < 128){
        int r = t;
        float ad;
        if (sx){ float2 d = ((const float2*)aDxo)[g*128+r]; ad = h ? d.y : d.x; }
        else   { ad = h ? aDi[r].y : aDi[r].x; }
        int b = begs[r]-gbeg, e = begs[r+1]-gbeg;
        float rs = 0.f;
        unsigned short* Pr = (unsigned short*)Pm + r*136;
        const float2* aSt = sx ? aSx : aSi;
        for (int j=b; j<e; ++j){
          int s = srcs[gbeg + j];
          float as = h ? aSt[s].y : aSt[s].x;
          float p = __expf(lrelu(as + ad));
          bf16 ov; *(unsigned short*)&ov = Pr[s];
          Pr[s] = f2bu(b2f(ov) + p);
          rs += p;
        }
        if (sx == 0){
          float as = h ? aSt[r].y : aSt[r].x;
          float p = __expf(lrelu(as + ad));
          bf16 ov; *(unsigned short*)&ov = Pr[r];
          Pr[r] = f2bu(b2f(ov) + p);
          rs += p;
        }
        rsum[r] = rs;
      }
      __syncthreads();
      f32x4 a2[2];
      a2[0] = (f32x4){0.f,0.f,0.f,0.f}; a2[1] = (f32x4){0.f,0.f,0.f,0.f};
      #pragma unroll
      for (int ks=0;ks<4;ks++){
        short8v af = *(const short8v*)((const unsigned short*)Pm + (w*16+lr)*136 + ks*32 + lg*8);
        #pragma unroll
        for (int j=0;j<2;j++){
          short8v bfr = *(const short8v*)((const unsigned short*)Ft + (j*16+lr)*136 + ks*32 + lg*8);
          a2[j] = __builtin_amdgcn_mfma_f32_16x16x32_bf16(af, bfr, a2[j], 0, 0, 0);
        }
      }
      #pragma unroll
      for (int rg=0; rg<4; ++rg){
        int rrow = w*16 + lg*4 + rg;
        float rinv = 1.f / (rsum[rrow] + 1e-16f);
        size_t n = (size_t)g*128 + rrow;
        #pragma unroll
        for (int j=0;j<2;j++){
          int c = h*32 + j*16 + lr;
          float o = a2[j][rg]*rinv + atab[(sx?256:192) + c];
          repout[n*128 + col_base + c] = f2b(o);
        }
      }
      __syncthreads();
    }
  }
}

// ---------------- graph LayerNorm + ELU, single-pass, d_out-resident (validated r16) ----------------
__global__ __launch_bounds__(512) void graph_ln_m(bf16* R_, size_t off_t_bf, size_t off_t_f32,
    const int* __restrict__ fsel, const float* __restrict__ wv, const float* __restrict__ bv){
  __shared__ float sh1[8], sh2[8];
  int g = blockIdx.x, t = threadIdx.x;
  int side = g >> 10, gl = g & 1023;
  size_t soff = side ? ((*fsel) ? off_t_f32 : off_t_bf) : 0;
  unsigned short* Ru = (unsigned short*)(R_ + soff + (size_t)gl*16384);
  short8v v[4];
  #pragma unroll
  for (int q=0;q<4;q++) v[q] = *(short8v*)(Ru + q*4096 + t*8);
  float s1=0.f, s2=0.f;
  #pragma unroll
  for (int q=0;q<4;q++)
    #pragma unroll
    for (int j=0;j<8;j++){
      bf16 b; *(unsigned short*)&b = ((unsigned short*)&v[q])[j];
      float x = b2f(b); s1 += x; s2 += x*x;
    }
  #pragma unroll
  for (int o=32;o;o>>=1){ s1 += __shfl_xor(s1,o); s2 += __shfl_xor(s2,o); }
  if ((t&63)==0){ sh1[t>>6]=s1; sh2[t>>6]=s2; }
  __syncthreads();
  float S1=0.f,S2=0.f;
  #pragma unroll
  for (int i=0;i<8;i++){ S1+=sh1[i]; S2+=sh2[i]; }
  float mean = S1 * (1.f/16384.f);
  float var = fmaxf(S2*(1.f/16384.f) - mean*mean, 0.f);
  float rstd = rsqrtf(var + 1e-5f);
  #pragma unroll
  for (int q=0;q<4;q++){
    short8v ov;
    #pragma unroll
    for (int j=0;j<8;j++){
      int c = (t*8 + j) & 127;
      bf16 b; *(unsigned short*)&b = ((unsigned short*)&v[q])[j];
      float y = (b2f(b)-mean)*rstd*wv[c] + bv[c];
      ((unsigned short*)&ov)[j] = f2bu(y>0.f ? y : expm1f(y));
    }
    *(short8v*)(Ru + q*4096 + t*8) = ov;
  }
}

// ---------------- pool GEMM (validated r16): d_out rep -> AB (ws), fused aSp/aDp ----------------
__global__ __launch_bounds__(512) void gemm_pool(const bf16* __restrict__ repbase, size_t rept_bf, size_t rept_f32,
    const bf16* __restrict__ Wtp, const float* __restrict__ sm,
    bf16* __restrict__ AB_h, bf16* __restrict__ AB_t,
    float* __restrict__ aSp_h, float* __restrict__ aDp_h,
    float* __restrict__ aSp_t, float* __restrict__ aDp_t,
    const int* __restrict__ fsel){
  __shared__ bf16 WtL[16384];
  __shared__ float attL[256];
  int side = blockIdx.x >> 10;
  int bx = blockIdx.x & 1023;
  size_t rept = (*fsel) ? rept_f32 : rept_bf;
  const unsigned short* A = (const unsigned short*)(repbase + (side ? rept : 0));
  bf16* C = side ? AB_t : AB_h;
  float* oS = side ? aSp_t : aSp_h;
  float* oD = side ? aDp_t : aDp_h;
  int tid = threadIdx.x;
  {
    const short8v* src = (const short8v*)Wtp;
    short8v* dst = (short8v*)WtL;
    #pragma unroll
    for (int i=0;i<4;i++) dst[tid + i*512] = src[tid + i*512];
    if (tid < 256) attL[tid] = sm[(tid<128) ? 192+tid : 320+(tid-128)];
  }
  __syncthreads();
  int w = tid >> 6, l = tid & 63;
  int lr = l & 15, lg = l >> 4;
  size_t row = (size_t)bx*128 + w*16 + lr;
  f32x4 acc[8];
  #pragma unroll
  for (int nt=0;nt<8;nt++) acc[nt] = (f32x4){0.f,0.f,0.f,0.f};
  #pragma unroll
  for (int ks=0;ks<4;ks++){
    short8v af = *(const short8v*)(A + row*128 + ks*32 + lg*8);
    #pragma unroll
    for (int nt=0;nt<8;nt++){
      short8v bfr = *(const short8v*)((const unsigned short*)WtL + (size_t)((nt*4+ks)*64 + l)*8);
      acc[nt] = __builtin_amdgcn_mfma_f32_16x16x32_bf16(af, bfr, acc[nt], 0, 0, 0);
    }
  }
  size_t crow = (size_t)bx*128 + w*16 + lg*4;
  #pragma unroll
  for (int nt=0;nt<8;nt++)
    #pragma unroll
    for (int r=0;r<4;r++)
      C[(crow + r)*128 + nt*16 + lr] = f2b(acc[nt][r]);
  #pragma unroll
  for (int rg=0; rg<4; ++rg){
    float pS0=0.f,pS1=0.f,pD0=0.f,pD1=0.f;
    #pragma unroll
    for (int nt=0;nt<8;nt++){
      float v = acc[nt][rg];
      int c = nt*16 + lr;
      float a=attL[c], b=attL[128+c];
      if (nt<4){ pS0+=v*a; pD0+=v*b; } else { pS1+=v*a; pD1+=v*b; }
    }
    #pragma unroll
    for (int o=1;o<16;o<<=1){
      pS0+=__shfl_xor(pS0,o); pS1+=__shfl_xor(pS1,o);
      pD0+=__shfl_xor(pD0,o); pD1+=__shfl_xor(pD1,o);
    }
    if (lr == 0){
      size_t n = crow + rg;
      oS[n*2]=pS0; oS[n*2+1]=pS1;
      oD[n*2]=pD0; oD[n*2+1]=pD1;
    }
  }
}

// ---------------- GAT aggregation v6 (validated rounds 12/16) ----------------
struct GatSet {
  const int* offs;
  const unsigned char* srcs;
  const bf16* F;
  const float* aS;
  const float* aD;
  const float* bias;
  int col_in;
  int self_loops;
  int col_off;
  int pad;
  size_t obase_bf, obase_f32, gbase;
};
struct GatSet4 { GatSet s[4]; };

template<int FD>
__global__ __launch_bounds__(512) void gat_mfma(GatSet4 sets, void* out,
    const int* __restrict__ fp, const int* __restrict__ fsel){
  constexpr int NH = FD/2;
  constexpr int NT = NH/16;
  constexpr int KSH = (FD==64)?5:6;
  __shared__ bf16 Ft[NH*136];
  __shared__ bf16 Pm[128*136];
  __shared__ float2 aSs[128];
  __shared__ float rsum[128];
  __shared__ unsigned char ss[EMAX];
  __shared__ int begs[129];
  const GatSet S = sets.s[blockIdx.y];
  int fo = fp ? *fp : -1;
  size_t obase = (fsel && *fsel) ? S.obase_f32 : S.obase_bf;
  int g = blockIdx.x, t = threadIdx.x;

  if (t < 129) begs[t] = S.offs[g*128 + t];
  if (t >= 256 && t < 384) aSs[t-256] = ((const float2*)S.aS)[g*128 + (t-256)];
  __syncthreads();
  int gbeg = begs[0];
  int Eg = min(begs[128] - gbeg, EMAX);
  int w = t >> 6, l = t & 63, lr = l & 15, lg = l >> 4;

  #pragma unroll
  for (int h=0; h<2; ++h){
    for (int i=t; i<128*68; i+=512) ((unsigned int*)Pm)[i] = 0;
    if (h==0) for (int i=t; i<Eg; i+=512) ss[i] = S.srcs[gbeg + i];
    __syncthreads();
    if (t < 128){
      int r = t;
      float ad = S.aD[(size_t)(g*128+r)*2 + h];
      int b = begs[r]-gbeg, e = min(begs[r+1]-gbeg, EMAX);
      float rs = 0.f;
      unsigned short* Pr = (unsigned short*)Pm + r*136;
      for (int j=b; j<e; ++j){
        int s = ss[j];
        float2 as2 = aSs[s];
        float p = __expf(lrelu((h ? as2.y : as2.x) + ad));
        bf16 ov; *(unsigned short*)&ov = Pr[s];
        Pr[s] = f2bu(b2f(ov) + p);
        rs += p;
      }
      if (S.self_loops){
        float2 as2 = aSs[r];
        float p = __expf(lrelu((h ? as2.y : as2.x) + ad));
        bf16 ov; *(unsigned short*)&ov = Pr[r];
        Pr[r] = f2bu(b2f(ov) + p);
        rs += p;
      }
      rsum[r] = rs;
    } else {
      const unsigned short* Fu = (const unsigned short*)S.F;
      unsigned short* FtU = (unsigned short*)Ft;
      int ft = t - 128;
      for (int i=ft; i<NH*128; i+=384){
        int c = i & (NH-1), k = i >> KSH;
        FtU[c*136 + k] = Fu[((size_t)(g*128+k))*128 + S.col_in + h*NH + c];
      }
    }
    __syncthreads();
    f32x4 acc[NT];
    #pragma unroll
    for (int nt=0;nt<NT;nt++) acc[nt] = (f32x4){0.f,0.f,0.f,0.f};
    #pragma unroll
    for (int ks=0;ks<4;ks++){
      short8v af = *(const short8v*)((const unsigned short*)Pm + (w*16+lr)*136 + ks*32 + lg*8);
      #pragma unroll
      for (int nt=0;nt<NT;nt++){
        short8v bfr = *(const short8v*)((const unsigned short*)Ft + (nt*16 + lr)*136 + ks*32 + lg*8);
        acc[nt] = __builtin_amdgcn_mfma_f32_16x16x32_bf16(af, bfr, acc[nt], 0, 0, 0);
      }
    }
    #pragma unroll
    for (int rg=0; rg<4; ++rg){
      int rrow = w*16 + lg*4 + rg;
      float rinv = 1.f / (rsum[rrow] + 1e-16f);
      int n = g*128 + rrow;
      bool gw = (fp != nullptr) && (rrow == 127);
      #pragma unroll
      for (int nt=0;nt<NT;nt++){
        int c = h*NH + nt*16 + lr;
        float o = acc[nt][rg]*rinv + S.bias[c];
        size_t oi = obase + (size_t)n*128 + S.col_off + c;
        if (fo > 0){
          ((float*)out)[oi] = o;
          if (gw) ((float*)out)[S.gbase + (size_t)g*128 + c] = o;
        } else {
          ((bf16*)out)[oi] = f2b(o);
          if (gw) ((bf16*)out)[S.gbase + (size_t)g*128 + c] = f2b(o);
        }
      }
    }
    __syncthreads();
  }
}

extern "C" void kernel_launch(void* const* d_in, const int* in_sizes, int n_in,
                              void* d_out, int out_size, void* d_ws, size_t ws_size,
                              hipStream_t stream){
  (void)in_sizes; (void)n_in; (void)out_size; (void)ws_size;
  const void* h_x = d_in[0];
  const void* t_x = d_in[1];
  const int* h_ei = (const int*)d_in[2];
  const int* t_ei = (const int*)d_in[3];
  const int* b_ei = (const int*)d_in[4];

  // ---- workspace (~90 MB; < 96.7 MB proven round 4) ----
  char* base = (char*)d_ws;
  size_t off = 0;
  auto alloc = [&](size_t bytes)->char*{ char* p = base + off; off += (bytes + 255) & ~(size_t)255; return p; };
  bf16* AB_h     = (bf16*)alloc((size_t)NN*128*2);   // pool feats h
  bf16* AB_t     = (bf16*)alloc((size_t)NN*128*2);   // pool feats t
  unsigned short* pk = (unsigned short*)alloc((size_t)4*NE*2);
  unsigned char* srcs8 = (unsigned char*)alloc((size_t)4*NE);
  int* offs4     = (int*)alloc((size_t)4*(NN+1)*4);
  int* Hb        = (int*)alloc((size_t)4*NB*NG*4);
  int* Bb        = (int*)alloc((size_t)4*NB*NG*4);
  int* base_gs   = (int*)alloc((size_t)4*(NG+1)*4);
  float* aDx_h   = (float*)alloc((size_t)NN*2*4);
  float* aDx_t   = (float*)alloc((size_t)NN*2*4);
  float* aSp_h   = (float*)alloc((size_t)NN*2*4);
  float* aDp_h   = (float*)alloc((size_t)NN*2*4);
  float* aSp_t   = (float*)alloc((size_t)NN*2*4);
  float* aDp_t   = (float*)alloc((size_t)NN*2*4);
  bf16* Wtc      = (bf16*)alloc(16384*2);
  bf16* Wtp      = (bf16*)alloc(16384*2);
  float* vdst    = (float*)alloc(256*4);
  float* sm      = (float*)alloc(960*4);
  int* flag      = (int*)alloc(256);

  // rep scratch in d_out (validated r4-r16 layout): rep_h at 0; rep_t flag-dependent
  const size_t REPT_BF = (size_t)NN*128, REPT_F32 = (size_t)2*NN*128;

  detect_dtype<<<1,64,0,stream>>>((const unsigned short*)h_x, flag);

  EPtrs ep;
  ep.s0 = h_ei;      ep.d0 = h_ei + NE;
  ep.s1 = t_ei;      ep.d1 = t_ei + NE;
  ep.s2 = b_ei;      ep.d2 = b_ei + NE;
  ep.s3 = b_ei + NE; ep.d3 = b_ei;
  hist_bagg<<<dim3(NB,4),256,0,stream>>>(ep, Hb);
  scan_bagg<<<4,1024,0,stream>>>(Hb, Bb, base_gs);
  scatter_bagg<<<dim3(NB,4),256,0,stream>>>(ep, Bb, pk);
  build_csr<<<dim3(NG,4),256,0,stream>>>(pk, base_gs, srcs8, offs4);

  prep_kernel<<<1,256,0,stream>>>(d_in[9], d_in[13], d_in[14], d_in[16], d_in[18],
      d_in[10], d_in[11], d_in[15], d_in[19], d_in[20],
      d_in[12], d_in[17], d_in[21], d_in[22], d_in[23],
      Wtc, Wtp, vdst, sm, flag);

  avec_dx_m<<<65536,256,0,stream>>>(h_x, t_x, vdst, aDx_h, aDx_t, flag);

  const int* offs_h = offs4;
  const int* offs_t = offs4 + (NN+1);
  const int* offs_ht= offs4 + 2*(NN+1);
  const int* offs_th= offs4 + 3*(NN+1);
  const unsigned char* srcs_h = srcs8;
  const unsigned char* srcs_t = srcs8 + NE;
  const unsigned char* srcs_ht= srcs8 + (size_t)2*NE;
  const unsigned char* srcs_th= srcs8 + (size_t)3*NE;

  // ---- layer-1: full GEMM + both GATs per (graph, side); rep -> d_out scratch ----
  gat_l1v2<<<dim3(NG,2),512,0,stream>>>(h_x, t_x,
      offs_h, srcs_h, offs_t, srcs_t, offs_ht, srcs_ht, offs_th, srcs_th,
      aDx_h, aDx_t, (bf16*)d_out, REPT_BF, REPT_F32, Wtc, sm, flag);

  // ---- graph LayerNorm + ELU on d_out rep (both sides) ----
  graph_ln_m<<<2048,512,0,stream>>>((bf16*)d_out, REPT_BF, REPT_F32, flag, sm+704, sm+832);

  // ---- pool GEMM: d_out rep -> AB (ws) + fused logits ----
  gemm_pool<<<2048,512,0,stream>>>((const bf16*)d_out, REPT_BF, REPT_F32, Wtp, sm,
      AB_h, AB_t, aSp_h, aDp_h, aSp_t, aDp_t, flag);

  // ---- pool GATs -> d_out + gathers (validated v6) ----
  {
    size_t gb_h = (size_t)2*NN*128;
    size_t gb_t = gb_h + (size_t)NG*128;
    GatSet4 P;
    P.s[0] = { offs_h, srcs_h, AB_h, aSp_h, aDp_h, sm+576, 0, 1, 0, 0, 0,              0,              gb_h };
    P.s[1] = { offs_t, srcs_t, AB_t, aSp_t, aDp_t, sm+576, 0, 1, 0, 0, (size_t)NN*128, (size_t)NN*128, gb_t };
    P.s[2] = P.s[0]; P.s[3] = P.s[0];
    gat_mfma<128><<<dim3(NG,2),512,0,stream>>>(P, d_out, flag, flag);
  }
}

// Round 21
// 525.212 us; speedup vs baseline: 1.1741x; 1.1646x over previous
//
#include <hip/hip_runtime.h>
#include <hip/hip_bf16.h>

#define NN 131072   // total nodes (1024 graphs x 128)
#define NG 1024     // graphs
#define NE 1048576  // edges per edge set
#define EB 16384    // edges per binning block
#define NB 64       // binning blocks per set (NE/EB)
#define EMAX 1536   // per-graph edge cap (gat_mfma staging only)

typedef __hip_bfloat16 bf16;
typedef __attribute__((ext_vector_type(8))) short short8v;
typedef __attribute__((ext_vector_type(4))) float f32x4;

__device__ __forceinline__ float b2f(bf16 v){ return __bfloat162float(v); }
__device__ __forceinline__ bf16 f2b(float v){ return __float2bfloat16(v); }
__device__ __forceinline__ unsigned short f2bu(float v){ bf16 b = f2b(v); return *(unsigned short*)&b; }
__device__ __forceinline__ float eluf(float x){ return x > 0.f ? x : expm1f(x); }
__device__ __forceinline__ float lrelu(float x){ return x >= 0.f ? x : 0.2f*x; }

__device__ __forceinline__ float ldx(const void* p, size_t i, int f){
  return f ? ((const float*)p)[i] : b2f(((const bf16*)p)[i]);
}

struct EPtrs { const int *s0,*d0,*s1,*d1,*s2,*d2,*s3,*d3; };

// ---------------- input dtype probe (validated round 4) ----------------
__global__ void detect_dtype(const unsigned short* __restrict__ x, int* __restrict__ flag){
  if (blockIdx.x==0 && threadIdx.x==0){
    int bad = 0;
    for (int i=0;i<2048;i++){
      unsigned short e = (x[i] >> 7) & 0xFF;
      if (e == 0xFF) bad++;
      else if (e >= 0x90) bad++;
      else if (e != 0 && e < 0x60) bad++;
    }
    *flag = (bad > 64) ? 1 : 0;
  }
}

// ---------------- CSR build (validated round 7): block-aggregated graph binning ----------------
__global__ __launch_bounds__(256) void hist_bagg(EPtrs ep, int* __restrict__ Hb){
  __shared__ int cnt[NG];
  int set = blockIdx.y, blk = blockIdx.x, t = threadIdx.x;
  const int* dp = set==0 ? ep.d0 : set==1 ? ep.d1 : set==2 ? ep.d2 : ep.d3;
  for (int i=t;i<NG;i+=256) cnt[i]=0;
  __syncthreads();
  int e0 = blk*EB;
  for (int i=t;i<EB;i+=256) atomicAdd(&cnt[dp[e0+i]>>7],1);
  __syncthreads();
  for (int i=t;i<NG;i+=256) Hb[((size_t)set*NB+blk)*NG+i] = cnt[i];
}

__global__ __launch_bounds__(1024) void scan_bagg(const int* __restrict__ Hb, int* __restrict__ Bb,
                                                  int* __restrict__ base_gs){
  __shared__ int sh[1024];
  int set = blockIdx.x, t = threadIdx.x;
  int run = 0;
  for (int b=0;b<NB;b++){
    int v = Hb[((size_t)set*NB + b)*NG + t];
    Bb[((size_t)set*NB + b)*NG + t] = run;
    run += v;
  }
  int val = run; sh[t] = run; __syncthreads();
  for (int d=1; d<1024; d<<=1){
    int add = (t>=d)? sh[t-d] : 0; __syncthreads();
    val += add; sh[t] = val; __syncthreads();
  }
  int binbase = val - run;
  base_gs[set*(NG+1) + t] = binbase;
  if (t==1023) base_gs[set*(NG+1)+NG] = val;   // == NE
  for (int b=0;b<NB;b++) Bb[((size_t)set*NB + b)*NG + t] += binbase;
}

__global__ __launch_bounds__(256) void scatter_bagg(EPtrs ep, const int* __restrict__ Bb,
                                                    unsigned short* __restrict__ pk){
  __shared__ int cur[NG];
  int set = blockIdx.y, blk = blockIdx.x, t = threadIdx.x;
  const int* sp = set==0 ? ep.s0 : set==1 ? ep.s1 : set==2 ? ep.s2 : ep.s3;
  const int* dp = set==0 ? ep.d0 : set==1 ? ep.d1 : set==2 ? ep.d2 : ep.d3;
  for (int i=t;i<NG;i+=256) cur[i] = Bb[((size_t)set*NB+blk)*NG+i];
  __syncthreads();
  int e0 = blk*EB;
  for (int i=t;i<EB;i+=256){
    int e = e0+i;
    int d = dp[e], s = sp[e];
    int p = atomicAdd(&cur[d>>7],1);
    pk[(size_t)set*NE + p] = (unsigned short)(((d & 127) << 8) | (s & 127));
  }
}

__global__ __launch_bounds__(256) void build_csr(const unsigned short* __restrict__ pk, const int* __restrict__ base,
                                                 unsigned char* __restrict__ srcs8, int* __restrict__ offs4){
  __shared__ int hist[128], excl[128], cur[128];
  __shared__ unsigned char ob[8192];
  int set = blockIdx.y, g = blockIdx.x, t = threadIdx.x;
  int n0 = base[set*(NG+1) + g], n1 = base[set*(NG+1) + g + 1];
  int cnt = min(n1 - n0, 8192);
  if (t < 128) hist[t] = 0;
  __syncthreads();
  const unsigned short* PK = pk + (size_t)set*NE + n0;
  for (int i=t; i<cnt; i+=256) atomicAdd(&hist[PK[i]>>8], 1);
  __syncthreads();
  if (t < 128) excl[t] = hist[t];
  __syncthreads();
  for (int d=1; d<128; d<<=1){
    int v = (t < 128 && t >= d) ? excl[t-d] : 0;
    __syncthreads();
    if (t < 128) excl[t] += v;
    __syncthreads();
  }
  if (t < 128){
    int e_ = excl[t] - hist[t];
    cur[t] = e_;
    offs4[(size_t)set*(NN+1) + g*128 + t] = n0 + e_;
  }
  if (g == NG-1 && t == 0) offs4[(size_t)set*(NN+1) + NN] = NE;
  __syncthreads();
  for (int i=t; i<cnt; i+=256){
    unsigned short v = PK[i];
    int p = atomicAdd(&cur[v>>8], 1);
    ob[p] = (unsigned char)(v & 127);
  }
  __syncthreads();
  unsigned char* S = srcs8 + (size_t)set*NE + n0;
  for (int i=t; i<cnt; i+=256) S[i] = ob[i];
}

// ---------------- weight prep (validated rounds 4/8) ----------------
// sm: 0 att_is[64] | 64 att_id[64] | 128 att_xs[64] | 192 att_ps[128] | 320 att_pd[128] |
//     448 b_intra[64] | 512 b_inter[64] | 576 b_pool[128] | 704 ln_w[128] | 832 ln_b[128]
__global__ __launch_bounds__(256) void prep_kernel(
    const void* w_intra, const void* w_isrc, const void* w_idst, const void* att_xd, const void* w_pool,
    const void* att_is, const void* att_id, const void* att_xs,
    const void* att_ps, const void* att_pd,
    const void* b_intra, const void* b_inter, const void* b_pool,
    const void* ln_w, const void* ln_b,
    bf16* __restrict__ Wtc, bf16* __restrict__ Wtp, float* __restrict__ vdst, float* __restrict__ sm,
    const int* __restrict__ fp){
  int f = *fp;
  int t = threadIdx.x;
  for (int i=t; i<16384; i+=256){
    int j = i & 7, l = (i>>3) & 63, ks = (i>>9) & 3, nt = i >> 11;
    int k = ks*32 + ((l>>4)<<3) + j;
    int c = nt*16 + (l & 15);
    float w1 = (c < 64) ? ldx(w_intra, k*64 + c, f) : ldx(w_isrc, k*64 + (c-64), f);
    Wtc[i] = f2b(w1);
    Wtp[i] = f2b(ldx(w_pool, k*128 + c, f));
  }
  {
    int k = t>>1, h = t&1; float a = 0.f;
    for (int c=0;c<32;c++) a += ldx(w_idst, k*64 + h*32 + c, f) * ldx(att_xd, h*32 + c, f);
    vdst[t] = a;
  }
  if (t < 64){
    sm[t]     = ldx(att_is, t, f);
    sm[64+t]  = ldx(att_id, t, f);
    sm[128+t] = ldx(att_xs, t, f);
    sm[448+t] = ldx(b_intra, t, f);
    sm[512+t] = ldx(b_inter, t, f);
  }
  if (t < 128){
    sm[192+t] = ldx(att_ps, t, f);
    sm[320+t] = ldx(att_pd, t, f);
    sm[576+t] = ldx(b_pool, t, f);
    sm[704+t] = ldx(ln_w, t, f);
    sm[832+t] = ldx(ln_b, t, f);
  }
}

// ---------------- MFMA GEMM v3 + fused logits (validated round 16): layer-1 only ----------------
// attL layout: [0..127]=attA, [128..255]=attB, [256..319]=attC, [320..575]=vdst
template<int MODE>
__global__ __launch_bounds__(512) void gemm_fused(const void* Ah, const void* At,
    const bf16* __restrict__ Wt, bf16* __restrict__ Ch, bf16* __restrict__ Ct,
    const int* __restrict__ fp, const int* __restrict__ fsel, size_t t_aoff_bf, size_t t_aoff_f32,
    const float* __restrict__ vdst,
    const float* __restrict__ attA, const float* __restrict__ attB, const float* __restrict__ attC,
    float* __restrict__ oS_h, float* __restrict__ oD_h, float* __restrict__ oX_h, float* __restrict__ oDx_h,
    float* __restrict__ oS_t, float* __restrict__ oD_t, float* __restrict__ oX_t, float* __restrict__ oDx_t){
  constexpr bool ELU = (MODE==0);
  __shared__ bf16 WtL[16384];
  __shared__ float attL[576];
  int side = blockIdx.x >> 10;
  int bx = blockIdx.x & 1023;
  const void* A = side ? At : Ah;
  bf16* C = side ? Ct : Ch;
  float* oS = side ? oS_t : oS_h;
  float* oD = side ? oD_t : oD_h;
  float* oX = side ? oX_t : oX_h;
  float* oDx = side ? oDx_t : oDx_h;
  const bf16* Ab = (const bf16*)A + ((fp == nullptr && side) ? ((fsel && *fsel) ? t_aoff_f32 : t_aoff_bf) : 0);
  int tid = threadIdx.x;
  {
    const short8v* src = (const short8v*)Wt;
    short8v* dst = (short8v*)WtL;
    #pragma unroll
    for (int i=0;i<4;i++) dst[tid + i*512] = src[tid + i*512];
    if constexpr (MODE==0){
      for (int i=tid; i<576; i+=512){
        float v;
        if (i<128) v = attA[i];
        else if (i<256) v = attB[i-128];
        else if (i<320) v = attC[i-256];
        else v = vdst[i-320];
        attL[i] = v;
      }
    } else {
      if (tid < 256) attL[tid] = (tid<128) ? attA[tid] : attB[tid-128];
    }
  }
  __syncthreads();
  int w = tid >> 6, l = tid & 63;
  int lr = l & 15, lg = l >> 4;
  size_t row = (size_t)bx*128 + w*16 + lr;
  int f = fp ? *fp : 0;
  f32x4 acc[8];
  #pragma unroll
  for (int nt=0;nt<8;nt++) acc[nt] = (f32x4){0.f,0.f,0.f,0.f};
  float dx0 = 0.f, dx1 = 0.f;
  #pragma unroll
  for (int ks=0;ks<4;ks++){
    short8v af;
    size_t ab = row*128 + ks*32 + lg*8;
    if (fp){
      if (f){
        const float* Af = (const float*)A;
        #pragma unroll
        for (int j=0;j<8;j++){
          float v = Af[ab+j]; if (ELU) v = eluf(v);
          if constexpr (MODE==0){ int k = ks*32+lg*8+j; dx0 += v*attL[320+k*2]; dx1 += v*attL[320+k*2+1]; }
          ((unsigned short*)&af)[j] = f2bu(v);
        }
      } else {
        const unsigned short* Au = (const unsigned short*)A;
        short8v raw = *(const short8v*)(Au + ab);
        #pragma unroll
        for (int j=0;j<8;j++){
          bf16 b; *(unsigned short*)&b = ((unsigned short*)&raw)[j];
          float v = b2f(b); if (ELU) v = eluf(v);
          if constexpr (MODE==0){ int k = ks*32+lg*8+j; dx0 += v*attL[320+k*2]; dx1 += v*attL[320+k*2+1]; }
          ((unsigned short*)&af)[j] = f2bu(v);
        }
      }
    } else {
      af = *(const short8v*)((const unsigned short*)Ab + ab);
    }
    #pragma unroll
    for (int nt=0;nt<8;nt++){
      short8v bfr = *(const short8v*)((const unsigned short*)WtL + (size_t)((nt*4+ks)*64 + l)*8);
      acc[nt] = __builtin_amdgcn_mfma_f32_16x16x32_bf16(af, bfr, acc[nt], 0, 0, 0);
    }
  }
  if constexpr (MODE==0){
    dx0 += __shfl_xor(dx0, 16); dx0 += __shfl_xor(dx0, 32);
    dx1 += __shfl_xor(dx1, 16); dx1 += __shfl_xor(dx1, 32);
    if (lg == 0){ oDx[row*2] = dx0; oDx[row*2+1] = dx1; }
  }
  size_t crow = (size_t)bx*128 + w*16 + lg*4;
  #pragma unroll
  for (int nt=0;nt<8;nt++)
    #pragma unroll
    for (int r=0;r<4;r++)
      C[(crow + r)*128 + nt*16 + lr] = f2b(acc[nt][r]);
  #pragma unroll
  for (int rg=0; rg<4; ++rg){
    float pS0=0.f,pS1=0.f,pD0=0.f,pD1=0.f,pX0=0.f,pX1=0.f;
    #pragma unroll
    for (int nt=0;nt<8;nt++){
      float v = acc[nt][rg];
      int c = nt*16 + lr;
      if constexpr (MODE==0){
        if (nt<4){
          float a=attL[c], b=attL[128+c];
          if (nt<2){ pS0+=v*a; pD0+=v*b; } else { pS1+=v*a; pD1+=v*b; }
        } else {
          float xw=attL[256+(c-64)];
          if (nt<6) pX0+=v*xw; else pX1+=v*xw;
        }
      } else {
        float a=attL[c], b=attL[128+c];
        if (nt<4){ pS0+=v*a; pD0+=v*b; } else { pS1+=v*a; pD1+=v*b; }
      }
    }
    #pragma unroll
    for (int o=1;o<16;o<<=1){
      pS0+=__shfl_xor(pS0,o); pS1+=__shfl_xor(pS1,o);
      pD0+=__shfl_xor(pD0,o); pD1+=__shfl_xor(pD1,o);
      if constexpr (MODE==0){ pX0+=__shfl_xor(pX0,o); pX1+=__shfl_xor(pX1,o); }
    }
    if (lr == 0){
      size_t n = crow + rg;
      oS[n*2]=pS0; oS[n*2+1]=pS1;
      oD[n*2]=pD0; oD[n*2+1]=pD1;
      if constexpr (MODE==0){ oX[n*2]=pX0; oX[n*2+1]=pX1; }
    }
  }
}

// ---------------- pool GEMM with FUSED graph-LN + logits (new this round) ----------------
// Block bx = graph bx of side (rows bx*128..+127 = exactly the LN reduction scope).
// attL: 0-127 att_ps | 128-255 att_pd | 256-383 ln_w | 384-511 ln_b
__global__ __launch_bounds__(512) void gemm_pool_ln(const bf16* __restrict__ repbase,
    size_t rept_bf, size_t rept_f32,
    const bf16* __restrict__ Wtp, const float* __restrict__ sm,
    bf16* __restrict__ AB_h, bf16* __restrict__ AB_t,
    float* __restrict__ aSp_h, float* __restrict__ aDp_h,
    float* __restrict__ aSp_t, float* __restrict__ aDp_t,
    const int* __restrict__ fsel){
  __shared__ bf16 WtL[16384];
  __shared__ float attL[512];
  __shared__ float sh1[8], sh2[8];
  int side = blockIdx.x >> 10;
  int bx = blockIdx.x & 1023;
  size_t rept = (*fsel) ? rept_f32 : rept_bf;
  const unsigned short* A = (const unsigned short*)(repbase + (side ? rept : 0));
  bf16* C = side ? AB_t : AB_h;
  float* oS = side ? aSp_t : aSp_h;
  float* oD = side ? aDp_t : aDp_h;
  int tid = threadIdx.x;
  {
    const short8v* src = (const short8v*)Wtp;
    short8v* dst = (short8v*)WtL;
    #pragma unroll
    for (int i=0;i<4;i++) dst[tid + i*512] = src[tid + i*512];
    attL[tid] = sm[(tid<128) ? 192+tid : (tid<256) ? 320+(tid-128)
                 : (tid<384) ? 704+(tid-256) : 832+(tid-384)];
  }
  __syncthreads();
  int w = tid >> 6, l = tid & 63;
  int lr = l & 15, lg = l >> 4;
  size_t row = (size_t)bx*128 + w*16 + lr;
  // pass 1: load raw bf16 frags (held in 16 VGPRs), accumulate LN stats
  short8v raw[4];
  float s1 = 0.f, s2 = 0.f;
  #pragma unroll
  for (int ks=0;ks<4;ks++){
    raw[ks] = *(const short8v*)(A + row*128 + ks*32 + lg*8);
    #pragma unroll
    for (int j=0;j<8;j++){
      bf16 b; *(unsigned short*)&b = ((unsigned short*)&raw[ks])[j];
      float x = b2f(b); s1 += x; s2 += x*x;
    }
  }
  #pragma unroll
  for (int o=32;o;o>>=1){ s1 += __shfl_xor(s1,o); s2 += __shfl_xor(s2,o); }
  if (l==0){ sh1[w]=s1; sh2[w]=s2; }
  __syncthreads();
  float S1=0.f, S2=0.f;
  #pragma unroll
  for (int i=0;i<8;i++){ S1+=sh1[i]; S2+=sh2[i]; }
  float mean = S1 * (1.f/16384.f);
  float var = fmaxf(S2*(1.f/16384.f) - mean*mean, 0.f);
  float rstd = rsqrtf(var + 1e-5f);
  // pass 2: apply LN + elu, build A-frags, GEMM (validated fragment math)
  f32x4 acc[8];
  #pragma unroll
  for (int nt=0;nt<8;nt++) acc[nt] = (f32x4){0.f,0.f,0.f,0.f};
  #pragma unroll
  for (int ks=0;ks<4;ks++){
    short8v af;
    #pragma unroll
    for (int j=0;j<8;j++){
      int c = ks*32 + lg*8 + j;
      bf16 b; *(unsigned short*)&b = ((unsigned short*)&raw[ks])[j];
      float y = (b2f(b) - mean)*rstd*attL[256+c] + attL[384+c];
      ((unsigned short*)&af)[j] = f2bu(y > 0.f ? y : expm1f(y));
    }
    #pragma unroll
    for (int nt=0;nt<8;nt++){
      short8v bfr = *(const short8v*)((const unsigned short*)WtL + (size_t)((nt*4+ks)*64 + l)*8);
      acc[nt] = __builtin_amdgcn_mfma_f32_16x16x32_bf16(af, bfr, acc[nt], 0, 0, 0);
    }
  }
  size_t crow = (size_t)bx*128 + w*16 + lg*4;
  #pragma unroll
  for (int nt=0;nt<8;nt++)
    #pragma unroll
    for (int r=0;r<4;r++)
      C[(crow + r)*128 + nt*16 + lr] = f2b(acc[nt][r]);
  #pragma unroll
  for (int rg=0; rg<4; ++rg){
    float pS0=0.f,pS1=0.f,pD0=0.f,pD1=0.f;
    #pragma unroll
    for (int nt=0;nt<8;nt++){
      float v = acc[nt][rg];
      int c = nt*16 + lr;
      float a=attL[c], b=attL[128+c];
      if (nt<4){ pS0+=v*a; pD0+=v*b; } else { pS1+=v*a; pD1+=v*b; }
    }
    #pragma unroll
    for (int o=1;o<16;o<<=1){
      pS0+=__shfl_xor(pS0,o); pS1+=__shfl_xor(pS1,o);
      pD0+=__shfl_xor(pD0,o); pD1+=__shfl_xor(pD1,o);
    }
    if (lr == 0){
      size_t n = crow + rg;
      oS[n*2]=pS0; oS[n*2+1]=pS1;
      oD[n*2]=pD0; oD[n*2+1]=pD1;
    }
  }
}

// ---------------- GAT aggregation v6 (validated rounds 12/16) ----------------
struct GatSet {
  const int* offs;
  const unsigned char* srcs;
  const bf16* F;
  const float* aS;
  const float* aD;
  const float* bias;
  int col_in;
  int self_loops;
  int col_off;
  int pad;
  size_t obase_bf, obase_f32, gbase;
};
struct GatSet4 { GatSet s[4]; };

template<int FD>
__global__ __launch_bounds__(512) void gat_mfma(GatSet4 sets, void* out,
    const int* __restrict__ fp, const int* __restrict__ fsel){
  constexpr int NH = FD/2;
  constexpr int NT = NH/16;
  constexpr int KSH = (FD==64)?5:6;
  __shared__ bf16 Ft[NH*136];
  __shared__ bf16 Pm[128*136];
  __shared__ float2 aSs[128];
  __shared__ float rsum[128];
  __shared__ unsigned char ss[EMAX];
  __shared__ int begs[129];
  const GatSet S = sets.s[blockIdx.y];
  int fo = fp ? *fp : -1;
  size_t obase = (fsel && *fsel) ? S.obase_f32 : S.obase_bf;
  int g = blockIdx.x, t = threadIdx.x;

  if (t < 129) begs[t] = S.offs[g*128 + t];
  if (t >= 256 && t < 384) aSs[t-256] = ((const float2*)S.aS)[g*128 + (t-256)];
  __syncthreads();
  int gbeg = begs[0];
  int Eg = min(begs[128] - gbeg, EMAX);
  int w = t >> 6, l = t & 63, lr = l & 15, lg = l >> 4;

  #pragma unroll
  for (int h=0; h<2; ++h){
    for (int i=t; i<128*68; i+=512) ((unsigned int*)Pm)[i] = 0;
    if (h==0) for (int i=t; i<Eg; i+=512) ss[i] = S.srcs[gbeg + i];
    __syncthreads();
    if (t < 128){
      int r = t;
      float ad = S.aD[(size_t)(g*128+r)*2 + h];
      int b = begs[r]-gbeg, e = min(begs[r+1]-gbeg, EMAX);
      float rs = 0.f;
      unsigned short* Pr = (unsigned short*)Pm + r*136;
      for (int j=b; j<e; ++j){
        int s = ss[j];
        float2 as2 = aSs[s];
        float p = __expf(lrelu((h ? as2.y : as2.x) + ad));
        bf16 ov; *(unsigned short*)&ov = Pr[s];
        Pr[s] = f2bu(b2f(ov) + p);
        rs += p;
      }
      if (S.self_loops){
        float2 as2 = aSs[r];
        float p = __expf(lrelu((h ? as2.y : as2.x) + ad));
        bf16 ov; *(unsigned short*)&ov = Pr[r];
        Pr[r] = f2bu(b2f(ov) + p);
        rs += p;
      }
      rsum[r] = rs;
    } else {
      const unsigned short* Fu = (const unsigned short*)S.F;
      unsigned short* FtU = (unsigned short*)Ft;
      int ft = t - 128;
      for (int i=ft; i<NH*128; i+=384){
        int c = i & (NH-1), k = i >> KSH;
        FtU[c*136 + k] = Fu[((size_t)(g*128+k))*128 + S.col_in + h*NH + c];
      }
    }
    __syncthreads();
    f32x4 acc[NT];
    #pragma unroll
    for (int nt=0;nt<NT;nt++) acc[nt] = (f32x4){0.f,0.f,0.f,0.f};
    #pragma unroll
    for (int ks=0;ks<4;ks++){
      short8v af = *(const short8v*)((const unsigned short*)Pm + (w*16+lr)*136 + ks*32 + lg*8);
      #pragma unroll
      for (int nt=0;nt<NT;nt++){
        short8v bfr = *(const short8v*)((const unsigned short*)Ft + (nt*16 + lr)*136 + ks*32 + lg*8);
        acc[nt] = __builtin_amdgcn_mfma_f32_16x16x32_bf16(af, bfr, acc[nt], 0, 0, 0);
      }
    }
    #pragma unroll
    for (int rg=0; rg<4; ++rg){
      int rrow = w*16 + lg*4 + rg;
      float rinv = 1.f / (rsum[rrow] + 1e-16f);
      int n = g*128 + rrow;
      bool gw = (fp != nullptr) && (rrow == 127);
      #pragma unroll
      for (int nt=0;nt<NT;nt++){
        int c = h*NH + nt*16 + lr;
        float o = acc[nt][rg]*rinv + S.bias[c];
        size_t oi = obase + (size_t)n*128 + S.col_off + c;
        if (fo > 0){
          ((float*)out)[oi] = o;
          if (gw) ((float*)out)[S.gbase + (size_t)g*128 + c] = o;
        } else {
          ((bf16*)out)[oi] = f2b(o);
          if (gw) ((bf16*)out)[S.gbase + (size_t)g*128 + c] = f2b(o);
        }
      }
    }
    __syncthreads();
  }
}

extern "C" void kernel_launch(void* const* d_in, const int* in_sizes, int n_in,
                              void* d_out, int out_size, void* d_ws, size_t ws_size,
                              hipStream_t stream){
  (void)in_sizes; (void)n_in; (void)out_size; (void)ws_size;
  const void* h_x = d_in[0];
  const void* t_x = d_in[1];
  const int* h_ei = (const int*)d_in[2];
  const int* t_ei = (const int*)d_in[3];
  const int* b_ei = (const int*)d_in[4];

  // ---- workspace (~92 MB; round 4 proved >=96.7 MB available) ----
  char* base = (char*)d_ws;
  size_t off = 0;
  auto alloc = [&](size_t bytes)->char*{ char* p = base + off; off += (bytes + 255) & ~(size_t)255; return p; };
  bf16* AB_h     = (bf16*)alloc((size_t)NN*128*2);
  bf16* AB_t     = (bf16*)alloc((size_t)NN*128*2);
  unsigned short* pk = (unsigned short*)alloc((size_t)4*NE*2);
  unsigned char* srcs8 = (unsigned char*)alloc((size_t)4*NE);
  int* offs4     = (int*)alloc((size_t)4*(NN+1)*4);
  int* Hb        = (int*)alloc((size_t)4*NB*NG*4);
  int* Bb        = (int*)alloc((size_t)4*NB*NG*4);
  int* base_gs   = (int*)alloc((size_t)4*(NG+1)*4);
  float* aSi_h   = (float*)alloc((size_t)NN*2*4);   // pool: aSp_h
  float* aDi_h   = (float*)alloc((size_t)NN*2*4);   // pool: aDp_h
  float* aSx_h   = (float*)alloc((size_t)NN*2*4);
  float* aSi_t   = (float*)alloc((size_t)NN*2*4);   // pool: aSp_t
  float* aDi_t   = (float*)alloc((size_t)NN*2*4);   // pool: aDp_t
  float* aSx_t   = (float*)alloc((size_t)NN*2*4);
  float* aDx_h   = (float*)alloc((size_t)NN*2*4);
  float* aDx_t   = (float*)alloc((size_t)NN*2*4);
  bf16* Wtc      = (bf16*)alloc(16384*2);
  bf16* Wtp      = (bf16*)alloc(16384*2);
  float* vdst    = (float*)alloc(256*4);
  float* sm      = (float*)alloc(960*4);
  int* flag      = (int*)alloc(256);

  const size_t REPT_BF = (size_t)NN*128, REPT_F32 = (size_t)2*NN*128;

  detect_dtype<<<1,64,0,stream>>>((const unsigned short*)h_x, flag);

  EPtrs ep;
  ep.s0 = h_ei;      ep.d0 = h_ei + NE;
  ep.s1 = t_ei;      ep.d1 = t_ei + NE;
  ep.s2 = b_ei;      ep.d2 = b_ei + NE;
  ep.s3 = b_ei + NE; ep.d3 = b_ei;
  hist_bagg<<<dim3(NB,4),256,0,stream>>>(ep, Hb);
  scan_bagg<<<4,1024,0,stream>>>(Hb, Bb, base_gs);
  scatter_bagg<<<dim3(NB,4),256,0,stream>>>(ep, Bb, pk);
  build_csr<<<dim3(NG,4),256,0,stream>>>(pk, base_gs, srcs8, offs4);

  prep_kernel<<<1,256,0,stream>>>(d_in[9], d_in[13], d_in[14], d_in[16], d_in[18],
      d_in[10], d_in[11], d_in[15], d_in[19], d_in[20],
      d_in[12], d_in[17], d_in[21], d_in[22], d_in[23],
      Wtc, Wtp, vdst, sm, flag);

  const int* offs_h = offs4;
  const int* offs_t = offs4 + (NN+1);
  const int* offs_ht= offs4 + 2*(NN+1);
  const int* offs_th= offs4 + 3*(NN+1);
  const unsigned char* srcs_h = srcs8;
  const unsigned char* srcs_t = srcs8 + NE;
  const unsigned char* srcs_ht= srcs8 + (size_t)2*NE;
  const unsigned char* srcs_th= srcs8 + (size_t)3*NE;

  // ---- layer-1 feature GEMMs with fused logits (h+t, 128 rows/block) ----
  gemm_fused<0><<<2048,512,0,stream>>>(h_x, t_x, Wtc, AB_h, AB_t, flag, nullptr, 0, 0,
      vdst, sm+0, sm+64, sm+128,
      aSi_h, aDi_h, aSx_h, aDx_h, aSi_t, aDi_t, aSx_t, aDx_t);

  // ---- merged layer-1 GATs: 4 sets, one dispatch (validated round 12/16) ----
  {
    GatSet4 L;
    L.s[0] = { offs_h,  srcs_h,  AB_h, aSi_h, aDi_h, sm+448, 0,  1, 0,  0, 0,        0,         0 };
    L.s[1] = { offs_t,  srcs_t,  AB_t, aSi_t, aDi_t, sm+448, 0,  1, 0,  0, REPT_BF,  REPT_F32,  0 };
    L.s[2] = { offs_ht, srcs_ht, AB_h, aSx_h, aDx_t, sm+512, 64, 0, 64, 0, REPT_BF,  REPT_F32,  0 };
    L.s[3] = { offs_th, srcs_th, AB_t, aSx_t, aDx_h, sm+512, 64, 0, 64, 0, 0,        0,         0 };
    gat_mfma<64><<<dim3(NG,4),512,0,stream>>>(L, d_out, nullptr, flag);
  }

  // ---- pool GEMM with FUSED graph-LN + logits: d_out rep -> AB (ws) ----
  gemm_pool_ln<<<2048,512,0,stream>>>((const bf16*)d_out, REPT_BF, REPT_F32, Wtp, sm,
      AB_h, AB_t, aSi_h, aDi_h, aSi_t, aDi_t, flag);

  // ---- pool GATs -> d_out + gathers (validated v6) ----
  {
    size_t gb_h = (size_t)2*NN*128;
    size_t gb_t = gb_h + (size_t)NG*128;
    GatSet4 P;
    P.s[0] = { offs_h, srcs_h, AB_h, aSi_h, aDi_h, sm+576, 0, 1, 0, 0, 0,              0,              gb_h };
    P.s[1] = { offs_t, srcs_t, AB_t, aSi_t, aDi_t, sm+576, 0, 1, 0, 0, (size_t)NN*128, (size_t)NN*128, gb_t };
    P.s[2] = P.s[0]; P.s[3] = P.s[0];
    gat_mfma<128><<<dim3(NG,2),512,0,stream>>>(P, d_out, flag, flag);
  }
}